// Round 1
// baseline (310.698 us; speedup 1.0000x reference)
//
#include <hip/hip_runtime.h>
#include <hip/hip_bf16.h>

#define NN 6144
#define INPUT 1024
#define HID 256

using frag  = __attribute__((ext_vector_type(8))) short;   // 8 bf16
using f32x4 = __attribute__((ext_vector_type(4))) float;

static __device__ __forceinline__ unsigned short bf16u(float x) {
    unsigned u = __float_as_uint(x);
    u += 0x7fff + ((u >> 16) & 1);     // RNE
    return (unsigned short)(u >> 16);
}

// ---------------- prep: X -> Xb bf16 (row-major), W -> Wt bf16 transposed ----------------
// Fused streaming pass. X converted ONCE here (was 4x inline in gemm1).
__global__ __launch_bounds__(256) void k_prep(const float* __restrict__ X,
                                              const float* __restrict__ W,
                                              unsigned short* __restrict__ Xb,
                                              unsigned short* __restrict__ Wt) {
    int b = blockIdx.x;
    if (b < 3072) {                         // X: 6144*1024 f32, 8 per thread
        int t = b * 256 + threadIdx.x;
        const float4* p = reinterpret_cast<const float4*>(X) + (size_t)t * 2;
        float4 x0 = p[0], x1 = p[1];
        frag v;
        v[0] = (short)bf16u(x0.x); v[1] = (short)bf16u(x0.y);
        v[2] = (short)bf16u(x0.z); v[3] = (short)bf16u(x0.w);
        v[4] = (short)bf16u(x1.x); v[5] = (short)bf16u(x1.y);
        v[6] = (short)bf16u(x1.z); v[7] = (short)bf16u(x1.w);
        *reinterpret_cast<frag*>(Xb + (size_t)t * 8) = v;
    } else {                                // W transpose: t = n*1024 + k
        int t = (b - 3072) * 256 + threadIdx.x;
        int n = t >> 10, k = t & 1023;
        Wt[t] = bf16u(W[k * HID + n]);
    }
}

// ---------------- GEMM1: hT = (X @ W)^T bf16, + fused s1/s2 ----------------
// grid (192, 4); block 256 = 4 waves. Tile M=32, N=64; wave n-slice 16.
// Xb already bf16: build = 1 16B load (prefetched 1 chunk ahead) + 1 ds_write.
__global__ __launch_bounds__(256) void k_gemm1(const unsigned short* __restrict__ Xb,
                                               const unsigned short* __restrict__ Wt,
                                               const float* __restrict__ a_edge,
                                               unsigned short* __restrict__ hT,
                                               float* __restrict__ s1,
                                               float* __restrict__ s2) {
    __shared__ unsigned short A[2][32][72];   // padded: 144 B row stride
    int t = threadIdx.x;
    int m = t >> 3, cg = t & 7;               // builder: row m (0..31), col-group cg
    int i0 = blockIdx.x * 32, n0 = blockIdx.y * 64;
    int w = t >> 6, l = t & 63, lm = l & 15, q = l >> 4;
    int nw = n0 + w * 16;

    const unsigned short* xrow = Xb + (size_t)(i0 + m) * INPUT + cg * 8;
    const unsigned short* brow = Wt + (size_t)(nw + lm) * INPUT + q * 8;

    f32x4 acc0 = {}, acc1 = {};
    frag av = *reinterpret_cast<const frag*>(xrow);   // prefetch chunk 0

    for (int c = 0; c < 16; c++) {
        int buf = c & 1;
        *reinterpret_cast<frag*>(&A[buf][m][cg * 8]) = av;
        if (c < 15) av = *reinterpret_cast<const frag*>(xrow + (c + 1) * 64);
        __syncthreads();

#pragma unroll
        for (int kk = 0; kk < 2; kk++) {
            frag a0 = *reinterpret_cast<const frag*>(&A[buf][lm][kk * 32 + q * 8]);
            frag a1 = *reinterpret_cast<const frag*>(&A[buf][16 + lm][kk * 32 + q * 8]);
            frag b  = *reinterpret_cast<const frag*>(brow + c * 64 + kk * 32);
            acc0 = __builtin_amdgcn_mfma_f32_16x16x32_bf16(a0, b, acc0, 0, 0, 0);
            acc1 = __builtin_amdgcn_mfma_f32_16x16x32_bf16(a1, b, acc1, 0, 0, 0);
        }
        // single barrier/chunk: next build writes buf^1; buf rewritten only after
        // the NEXT chunk's barrier, which follows every wave's reads of buf.
    }

    // hT write: C/D layout col=lm (n), row=q*4+r (m within 16-half)
    ushort4 o;
    o.x = bf16u(acc0[0]); o.y = bf16u(acc0[1]); o.z = bf16u(acc0[2]); o.w = bf16u(acc0[3]);
    *reinterpret_cast<ushort4*>(hT + (size_t)(nw + lm) * NN + i0 + q * 4) = o;
    o.x = bf16u(acc1[0]); o.y = bf16u(acc1[1]); o.z = bf16u(acc1[2]); o.w = bf16u(acc1[3]);
    *reinterpret_cast<ushort4*>(hT + (size_t)(nw + lm) * NN + i0 + 16 + q * 4) = o;

    // fused s1/s2: reduce over the 16 n of this wave's slice, few atomics
    float a1v = a_edge[nw + lm], a2v = a_edge[HID + nw + lm];
#pragma unroll
    for (int h = 0; h < 2; h++) {
        const f32x4& ac = h ? acc1 : acc0;
#pragma unroll
        for (int r = 0; r < 4; r++) {
            float v1 = ac[r] * a1v, v2 = ac[r] * a2v;
            v1 += __shfl_xor(v1, 1); v2 += __shfl_xor(v2, 1);
            v1 += __shfl_xor(v1, 2); v2 += __shfl_xor(v2, 2);
            v1 += __shfl_xor(v1, 4); v2 += __shfl_xor(v2, 4);
            v1 += __shfl_xor(v1, 8); v2 += __shfl_xor(v2, 8);
            if (lm == 0) {
                atomicAdd(&s1[i0 + h * 16 + q * 4 + r], v1);
                atomicAdd(&s2[i0 + h * 16 + q * 4 + r], v2);
            }
        }
    }
}

// ---------------- fused attention ----------------
// grid (192, 4); block 512 = 8 waves (was 4): 768 blocks x 8 waves = 24 waves/CU
// (75% occupancy cap vs previous 37.5%). Same tiling -> identical HBM/L2 traffic.
// M=32 rows/block, j-quarter 1536 cols, 12 chunks of 128. P double-buffered in LDS,
// one barrier per chunk. adj for chunk c+1 register-prefetched across the MFMA phase.
__global__ __launch_bounds__(512) void k_attn(const int* __restrict__ adj,
                                              const float* __restrict__ s1,
                                              const float* __restrict__ s2,
                                              const unsigned short* __restrict__ hT,
                                              float* __restrict__ U4,
                                              float* __restrict__ denom4) {
    __shared__ unsigned short P[2][32][136];   // 17408 B; 272 B row stride
    int t = threadIdx.x;
    int m = t >> 4, cg = t & 15;               // builder: row m (0..31), col-group cg (8 cols)
    int i0 = blockIdx.x * 32;
    int q4 = blockIdx.y;
    int j0 = q4 * 1536;
    int w = t >> 6, l = t & 63, lm = l & 15, q = l >> 4;

    float s1v = s1[i0 + m];
    const int*   arow = adj + (size_t)(i0 + m) * NN + j0 + cg * 8;
    const float* s2p  = s2 + j0 + cg * 8;

    // wave n-slice 32: covers 256 hT rows across 8 waves
    const unsigned short* brow[2];
#pragma unroll
    for (int nt = 0; nt < 2; nt++)
        brow[nt] = hT + (size_t)(w * 32 + nt * 16 + lm) * NN + j0 + q * 8;

    f32x4 acc[2][2] = {};
    float dsum = 0.f;

    // prefetch chunk 0's adj
    int4 ca0 = *reinterpret_cast<const int4*>(arow);
    int4 ca1 = *reinterpret_cast<const int4*>(arow + 4);

    for (int c = 0; c < 12; c++) {
        int buf = c & 1;
        int jc = c * 128;

        // issue next chunk's adj loads first: in flight across build+barrier+MFMA
        int4 na0, na1;
        if (c < 11) {
            na0 = *reinterpret_cast<const int4*>(arow + jc + 128);
            na1 = *reinterpret_cast<const int4*>(arow + jc + 132);
        }

        // ---- build P chunk from prefetched adj (8 elems/thread) ----
        float4 sv0 = *reinterpret_cast<const float4*>(s2p + jc);
        float4 sv1 = *reinterpret_cast<const float4*>(s2p + jc + 4);
        float sc, wv, p0, p1, p2, p3, p4, p5, p6, p7;
        sc = s1v + sv0.x; wv = fmaxf(sc, 0.2f * sc); p0 = ca0.x ? __expf(wv) : 0.f;
        sc = s1v + sv0.y; wv = fmaxf(sc, 0.2f * sc); p1 = ca0.y ? __expf(wv) : 0.f;
        sc = s1v + sv0.z; wv = fmaxf(sc, 0.2f * sc); p2 = ca0.z ? __expf(wv) : 0.f;
        sc = s1v + sv0.w; wv = fmaxf(sc, 0.2f * sc); p3 = ca0.w ? __expf(wv) : 0.f;
        sc = s1v + sv1.x; wv = fmaxf(sc, 0.2f * sc); p4 = ca1.x ? __expf(wv) : 0.f;
        sc = s1v + sv1.y; wv = fmaxf(sc, 0.2f * sc); p5 = ca1.y ? __expf(wv) : 0.f;
        sc = s1v + sv1.z; wv = fmaxf(sc, 0.2f * sc); p6 = ca1.z ? __expf(wv) : 0.f;
        sc = s1v + sv1.w; wv = fmaxf(sc, 0.2f * sc); p7 = ca1.w ? __expf(wv) : 0.f;
        dsum += ((p0 + p1) + (p2 + p3)) + ((p4 + p5) + (p6 + p7));
        frag pk;
        pk[0] = (short)bf16u(p0); pk[1] = (short)bf16u(p1);
        pk[2] = (short)bf16u(p2); pk[3] = (short)bf16u(p3);
        pk[4] = (short)bf16u(p4); pk[5] = (short)bf16u(p5);
        pk[6] = (short)bf16u(p6); pk[7] = (short)bf16u(p7);
        *reinterpret_cast<frag*>(&P[buf][m][cg * 8]) = pk;

        __syncthreads();

        // ---- consume: 4 k-steps x (2 A-halves x 2 B-frags) = 16 MFMA/wave ----
        __builtin_amdgcn_s_setprio(1);
#pragma unroll
        for (int kk = 0; kk < 4; kk++) {
            frag a0 = *reinterpret_cast<const frag*>(&P[buf][lm][kk * 32 + q * 8]);
            frag a1 = *reinterpret_cast<const frag*>(&P[buf][16 + lm][kk * 32 + q * 8]);
#pragma unroll
            for (int nt = 0; nt < 2; nt++) {
                frag b = *reinterpret_cast<const frag*>(brow[nt] + jc + kk * 32);
                acc[0][nt] = __builtin_amdgcn_mfma_f32_16x16x32_bf16(a0, b, acc[0][nt], 0, 0, 0);
                acc[1][nt] = __builtin_amdgcn_mfma_f32_16x16x32_bf16(a1, b, acc[1][nt], 0, 0, 0);
            }
        }
        __builtin_amdgcn_s_setprio(0);

        ca0 = na0; ca1 = na1;
        // single barrier per chunk: next build writes buf^1; buf rewritten only after
        // the NEXT chunk's barrier, which follows every wave's reads of buf.
    }

    // denom partial: builder lanes with same m are cg=0..15 in-wave -> reduce over cg
    float v = dsum;
    v += __shfl_xor(v, 1); v += __shfl_xor(v, 2);
    v += __shfl_xor(v, 4); v += __shfl_xor(v, 8);
    if (cg == 0) denom4[(size_t)q4 * NN + i0 + m] = v;

    // U4 partial: plain stores (no atomics)
    float* Ub = U4 + (size_t)q4 * NN * HID;
#pragma unroll
    for (int h = 0; h < 2; h++)
#pragma unroll
        for (int nt = 0; nt < 2; nt++)
#pragma unroll
            for (int r = 0; r < 4; r++)
                Ub[(size_t)(i0 + h * 16 + q * 4 + r) * HID + w * 32 + nt * 16 + lm] = acc[h][nt][r];
}

// ---------------- normalize: out = (sum_q U4) / (sum_q denom4) ----------------
__global__ __launch_bounds__(256) void k_norm(const float* __restrict__ U4,
                                              const float* __restrict__ denom4,
                                              float* __restrict__ out) {
    int i = blockIdx.x, t = threadIdx.x;
    size_t S = (size_t)NN * HID;
    size_t base = (size_t)i * HID + t;
    float u = U4[base] + U4[base + S] + U4[base + 2 * S] + U4[base + 3 * S];
    float d = denom4[i] + denom4[i + NN] + denom4[i + 2 * NN] + denom4[i + 3 * NN];
    out[base] = (d != 0.f) ? u / d : 0.f;
}

extern "C" void kernel_launch(void* const* d_in, const int* in_sizes, int n_in,
                              void* d_out, int out_size, void* d_ws, size_t ws_size,
                              hipStream_t stream) {
    const float* X      = (const float*)d_in[0];   // 6144x1024
    const float* W      = (const float*)d_in[1];   // 1024x256
    const float* a_edge = (const float*)d_in[2];   // 512
    const int*   adj    = (const int*)d_in[3];     // 6144x6144
    float* out = (float*)d_out;

    float* U4     = (float*)d_ws;                          // 4*NN*HID f32 (25.2 MB)
    float* denom4 = U4 + (size_t)4 * NN * HID;             // 4*NN
    float* s1     = denom4 + (size_t)4 * NN;               // NN
    float* s2     = s1 + NN;                               // NN
    unsigned short* hT = (unsigned short*)(s2 + NN);       // HID*NN bf16 (3.1 MB)
    unsigned short* Wt = hT + (size_t)HID * NN;            // HID*INPUT bf16 (0.5 MB)
    // Xb (12.6 MB) ALIASES U4: dead before k_attn fully overwrites U4.
    unsigned short* Xb = (unsigned short*)U4;

    hipMemsetAsync(s1, 0, 2 * NN * sizeof(float), stream);
    k_prep<<<3072 + INPUT * HID / 256, 256, 0, stream>>>(X, W, Xb, Wt);
    k_gemm1<<<dim3(NN / 32, HID / 64), 256, 0, stream>>>(Xb, Wt, a_edge, hT, s1, s2);
    k_attn<<<dim3(NN / 32, 4), 512, 0, stream>>>(adj, s1, s2, hT, U4, denom4);
    k_norm<<<NN, 256, 0, stream>>>(U4, denom4, out);
}

// Round 2
// 300.042 us; speedup vs baseline: 1.0355x; 1.0355x over previous
//
#include <hip/hip_runtime.h>
#include <hip/hip_bf16.h>

#define NN 6144
#define INPUT 1024
#define HID 256

using frag  = __attribute__((ext_vector_type(8))) short;   // 8 bf16
using f32x4 = __attribute__((ext_vector_type(4))) float;

static __device__ __forceinline__ unsigned short bf16u(float x) {
    unsigned u = __float_as_uint(x);
    u += 0x7fff + ((u >> 16) & 1);     // RNE
    return (unsigned short)(u >> 16);
}

// LDS-producer barrier WITHOUT the __syncthreads vmcnt(0) drain:
// ds_write visibility needs lgkmcnt(0) only; global prefetches stay in flight.
static __device__ __forceinline__ void lds_barrier() {
    asm volatile("s_waitcnt lgkmcnt(0)" ::: "memory");
    __builtin_amdgcn_s_barrier();
    __builtin_amdgcn_sched_barrier(0);   // no ds_read hoisting above the barrier
}

// ---------------- prep: X -> Xb bf16 (row-major), W -> Wt bf16 transposed ----------------
__global__ __launch_bounds__(256) void k_prep(const float* __restrict__ X,
                                              const float* __restrict__ W,
                                              unsigned short* __restrict__ Xb,
                                              unsigned short* __restrict__ Wt) {
    int b = blockIdx.x;
    if (b < 3072) {                         // X: 6144*1024 f32, 8 per thread
        int t = b * 256 + threadIdx.x;
        const float4* p = reinterpret_cast<const float4*>(X) + (size_t)t * 2;
        float4 x0 = p[0], x1 = p[1];
        frag v;
        v[0] = (short)bf16u(x0.x); v[1] = (short)bf16u(x0.y);
        v[2] = (short)bf16u(x0.z); v[3] = (short)bf16u(x0.w);
        v[4] = (short)bf16u(x1.x); v[5] = (short)bf16u(x1.y);
        v[6] = (short)bf16u(x1.z); v[7] = (short)bf16u(x1.w);
        *reinterpret_cast<frag*>(Xb + (size_t)t * 8) = v;
    } else {                                // W transpose: t = n*1024 + k
        int t = (b - 3072) * 256 + threadIdx.x;
        int n = t >> 10, k = t & 1023;
        Wt[t] = bf16u(W[k * HID + n]);
    }
}

// ---------------- GEMM1: hT = (X @ W)^T bf16, + fused s1/s2 ----------------
// grid (192, 4); block 256 = 4 waves. Tile M=32, N=64; wave n-slice 16.
// Counted-vmcnt barrier (lds_barrier): Xb and Wt loads stay in flight across it.
__global__ __launch_bounds__(256) void k_gemm1(const unsigned short* __restrict__ Xb,
                                               const unsigned short* __restrict__ Wt,
                                               const float* __restrict__ a_edge,
                                               unsigned short* __restrict__ hT,
                                               float* __restrict__ s1,
                                               float* __restrict__ s2) {
    __shared__ unsigned short A[2][32][72];   // padded: 144 B row stride
    int t = threadIdx.x;
    int m = t >> 3, cg = t & 7;               // builder: row m (0..31), col-group cg
    int i0 = blockIdx.x * 32, n0 = blockIdx.y * 64;
    int w = t >> 6, l = t & 63, lm = l & 15, q = l >> 4;
    int nw = n0 + w * 16;

    const unsigned short* xrow = Xb + (size_t)(i0 + m) * INPUT + cg * 8;
    const unsigned short* brow = Wt + (size_t)(nw + lm) * INPUT + q * 8;

    f32x4 acc0 = {}, acc1 = {};
    frag av = *reinterpret_cast<const frag*>(xrow);   // prefetch chunk 0's A

    for (int c = 0; c < 16; c++) {
        int buf = c & 1;
        // B frags for THIS chunk: issue before build+barrier, consume after.
        frag b0 = *reinterpret_cast<const frag*>(brow + c * 64);
        frag b1 = *reinterpret_cast<const frag*>(brow + c * 64 + 32);

        *reinterpret_cast<frag*>(&A[buf][m][cg * 8]) = av;
        if (c < 15) av = *reinterpret_cast<const frag*>(xrow + (c + 1) * 64);

        lds_barrier();

#pragma unroll
        for (int kk = 0; kk < 2; kk++) {
            frag a0 = *reinterpret_cast<const frag*>(&A[buf][lm][kk * 32 + q * 8]);
            frag a1 = *reinterpret_cast<const frag*>(&A[buf][16 + lm][kk * 32 + q * 8]);
            frag b  = kk ? b1 : b0;
            acc0 = __builtin_amdgcn_mfma_f32_16x16x32_bf16(a0, b, acc0, 0, 0, 0);
            acc1 = __builtin_amdgcn_mfma_f32_16x16x32_bf16(a1, b, acc1, 0, 0, 0);
        }
        // single barrier/chunk: next build writes buf^1; buf rewritten only after
        // the NEXT chunk's barrier, which follows every wave's reads of buf.
    }

    // hT write: C/D layout col=lm (n), row=q*4+r (m within 16-half)
    ushort4 o;
    o.x = bf16u(acc0[0]); o.y = bf16u(acc0[1]); o.z = bf16u(acc0[2]); o.w = bf16u(acc0[3]);
    *reinterpret_cast<ushort4*>(hT + (size_t)(nw + lm) * NN + i0 + q * 4) = o;
    o.x = bf16u(acc1[0]); o.y = bf16u(acc1[1]); o.z = bf16u(acc1[2]); o.w = bf16u(acc1[3]);
    *reinterpret_cast<ushort4*>(hT + (size_t)(nw + lm) * NN + i0 + 16 + q * 4) = o;

    // fused s1/s2: reduce over the 16 n of this wave's slice, few atomics
    float a1v = a_edge[nw + lm], a2v = a_edge[HID + nw + lm];
#pragma unroll
    for (int h = 0; h < 2; h++) {
        const f32x4& ac = h ? acc1 : acc0;
#pragma unroll
        for (int r = 0; r < 4; r++) {
            float v1 = ac[r] * a1v, v2 = ac[r] * a2v;
            v1 += __shfl_xor(v1, 1); v2 += __shfl_xor(v2, 1);
            v1 += __shfl_xor(v1, 2); v2 += __shfl_xor(v2, 2);
            v1 += __shfl_xor(v1, 4); v2 += __shfl_xor(v2, 4);
            v1 += __shfl_xor(v1, 8); v2 += __shfl_xor(v2, 8);
            if (lm == 0) {
                atomicAdd(&s1[i0 + h * 16 + q * 4 + r], v1);
                atomicAdd(&s2[i0 + h * 16 + q * 4 + r], v2);
            }
        }
    }
}

// ---------------- fused attention ----------------
// grid (192, 4); block 512 = 8 waves. M=32 rows/block, j-quarter 1536 cols,
// 12 chunks of 128. P double-buffered in LDS, ONE counted-vmcnt barrier per chunk.
// Per chunk: issue this chunk's 8 B-frags (hT, L2) FIRST; issue next chunk's
// adj+s2; build P from last chunk's prefetched adj/s2; lds_barrier; MFMA from regs.
// All global latency (adj HBM ~900cy, B L2 ~250cy) now overlaps build+barrier+MFMA
// instead of draining at __syncthreads' vmcnt(0).
__global__ __launch_bounds__(512) void k_attn(const int* __restrict__ adj,
                                              const float* __restrict__ s1,
                                              const float* __restrict__ s2,
                                              const unsigned short* __restrict__ hT,
                                              float* __restrict__ U4,
                                              float* __restrict__ denom4) {
    __shared__ unsigned short P[2][32][136];   // 17408 B; 272 B row stride
    int t = threadIdx.x;
    int m = t >> 4, cg = t & 15;               // builder: row m (0..31), col-group cg (8 cols)
    int i0 = blockIdx.x * 32;
    int q4 = blockIdx.y;
    int j0 = q4 * 1536;
    int w = t >> 6, l = t & 63, lm = l & 15, q = l >> 4;

    float s1v = s1[i0 + m];
    const int*   arow = adj + (size_t)(i0 + m) * NN + j0 + cg * 8;
    const float* s2p  = s2 + j0 + cg * 8;

    // wave n-slice 32: 8 waves cover 256 hT rows
    const unsigned short* brow[2];
#pragma unroll
    for (int nt = 0; nt < 2; nt++)
        brow[nt] = hT + (size_t)(w * 32 + nt * 16 + lm) * NN + j0 + q * 8;

    f32x4 acc[2][2] = {};
    float dsum = 0.f;

    // prefetch chunk 0's adj + s2
    int4   ca0 = *reinterpret_cast<const int4*>(arow);
    int4   ca1 = *reinterpret_cast<const int4*>(arow + 4);
    float4 cs0 = *reinterpret_cast<const float4*>(s2p);
    float4 cs1 = *reinterpret_cast<const float4*>(s2p + 4);

    for (int c = 0; c < 12; c++) {
        int buf = c & 1;
        int jc = c * 128;

        // ---- this chunk's B frags: issue now, consumed after build+barrier ----
        frag bf[8];
#pragma unroll
        for (int kk = 0; kk < 4; kk++)
#pragma unroll
            for (int nt = 0; nt < 2; nt++)
                bf[kk * 2 + nt] = *reinterpret_cast<const frag*>(brow[nt] + jc + kk * 32);

        // ---- next chunk's adj + s2: in flight across build+barrier+MFMA ----
        int4 na0 = {}, na1 = {};
        float4 ns0 = {}, ns1 = {};
        if (c < 11) {
            na0 = *reinterpret_cast<const int4*>(arow + jc + 128);
            na1 = *reinterpret_cast<const int4*>(arow + jc + 132);
            ns0 = *reinterpret_cast<const float4*>(s2p + jc + 128);
            ns1 = *reinterpret_cast<const float4*>(s2p + jc + 132);
        }

        // ---- build P chunk from prefetched regs (8 elems/thread, VALU only) ----
        float sc, wv, p0, p1, p2, p3, p4, p5, p6, p7;
        sc = s1v + cs0.x; wv = fmaxf(sc, 0.2f * sc); p0 = ca0.x ? __expf(wv) : 0.f;
        sc = s1v + cs0.y; wv = fmaxf(sc, 0.2f * sc); p1 = ca0.y ? __expf(wv) : 0.f;
        sc = s1v + cs0.z; wv = fmaxf(sc, 0.2f * sc); p2 = ca0.z ? __expf(wv) : 0.f;
        sc = s1v + cs0.w; wv = fmaxf(sc, 0.2f * sc); p3 = ca0.w ? __expf(wv) : 0.f;
        sc = s1v + cs1.x; wv = fmaxf(sc, 0.2f * sc); p4 = ca1.x ? __expf(wv) : 0.f;
        sc = s1v + cs1.y; wv = fmaxf(sc, 0.2f * sc); p5 = ca1.y ? __expf(wv) : 0.f;
        sc = s1v + cs1.z; wv = fmaxf(sc, 0.2f * sc); p6 = ca1.z ? __expf(wv) : 0.f;
        sc = s1v + cs1.w; wv = fmaxf(sc, 0.2f * sc); p7 = ca1.w ? __expf(wv) : 0.f;
        dsum += ((p0 + p1) + (p2 + p3)) + ((p4 + p5) + (p6 + p7));
        frag pk;
        pk[0] = (short)bf16u(p0); pk[1] = (short)bf16u(p1);
        pk[2] = (short)bf16u(p2); pk[3] = (short)bf16u(p3);
        pk[4] = (short)bf16u(p4); pk[5] = (short)bf16u(p5);
        pk[6] = (short)bf16u(p6); pk[7] = (short)bf16u(p7);
        *reinterpret_cast<frag*>(&P[buf][m][cg * 8]) = pk;

        lds_barrier();

        // ---- consume: 4 k-steps x (2 A-halves x 2 B-frags) = 16 MFMA/wave ----
        __builtin_amdgcn_s_setprio(1);
#pragma unroll
        for (int kk = 0; kk < 4; kk++) {
            frag a0 = *reinterpret_cast<const frag*>(&P[buf][lm][kk * 32 + q * 8]);
            frag a1 = *reinterpret_cast<const frag*>(&P[buf][16 + lm][kk * 32 + q * 8]);
#pragma unroll
            for (int nt = 0; nt < 2; nt++) {
                acc[0][nt] = __builtin_amdgcn_mfma_f32_16x16x32_bf16(a0, bf[kk * 2 + nt], acc[0][nt], 0, 0, 0);
                acc[1][nt] = __builtin_amdgcn_mfma_f32_16x16x32_bf16(a1, bf[kk * 2 + nt], acc[1][nt], 0, 0, 0);
            }
        }
        __builtin_amdgcn_s_setprio(0);

        ca0 = na0; ca1 = na1; cs0 = ns0; cs1 = ns1;
        // single barrier per chunk: next build writes buf^1; buf rewritten only after
        // the NEXT chunk's barrier, which follows every wave's reads of buf.
    }

    // denom partial: builder lanes with same m are cg=0..15 in-wave -> reduce over cg
    float v = dsum;
    v += __shfl_xor(v, 1); v += __shfl_xor(v, 2);
    v += __shfl_xor(v, 4); v += __shfl_xor(v, 8);
    if (cg == 0) denom4[(size_t)q4 * NN + i0 + m] = v;

    // U4 partial: plain stores (no atomics)
    float* Ub = U4 + (size_t)q4 * NN * HID;
#pragma unroll
    for (int h = 0; h < 2; h++)
#pragma unroll
        for (int nt = 0; nt < 2; nt++)
#pragma unroll
            for (int r = 0; r < 4; r++)
                Ub[(size_t)(i0 + h * 16 + q * 4 + r) * HID + w * 32 + nt * 16 + lm] = acc[h][nt][r];
}

// ---------------- normalize: out = (sum_q U4) / (sum_q denom4) ----------------
__global__ __launch_bounds__(256) void k_norm(const float* __restrict__ U4,
                                              const float* __restrict__ denom4,
                                              float* __restrict__ out) {
    int i = blockIdx.x, t = threadIdx.x;
    size_t S = (size_t)NN * HID;
    size_t base = (size_t)i * HID + t;
    float u = U4[base] + U4[base + S] + U4[base + 2 * S] + U4[base + 3 * S];
    float d = denom4[i] + denom4[i + NN] + denom4[i + 2 * NN] + denom4[i + 3 * NN];
    out[base] = (d != 0.f) ? u / d : 0.f;
}

extern "C" void kernel_launch(void* const* d_in, const int* in_sizes, int n_in,
                              void* d_out, int out_size, void* d_ws, size_t ws_size,
                              hipStream_t stream) {
    const float* X      = (const float*)d_in[0];   // 6144x1024
    const float* W      = (const float*)d_in[1];   // 1024x256
    const float* a_edge = (const float*)d_in[2];   // 512
    const int*   adj    = (const int*)d_in[3];     // 6144x6144
    float* out = (float*)d_out;

    float* U4     = (float*)d_ws;                          // 4*NN*HID f32 (25.2 MB)
    float* denom4 = U4 + (size_t)4 * NN * HID;             // 4*NN
    float* s1     = denom4 + (size_t)4 * NN;               // NN
    float* s2     = s1 + NN;                               // NN
    unsigned short* hT = (unsigned short*)(s2 + NN);       // HID*NN bf16 (3.1 MB)
    unsigned short* Wt = hT + (size_t)HID * NN;            // HID*INPUT bf16 (0.5 MB)
    // Xb (12.6 MB) ALIASES U4: dead before k_attn fully overwrites U4.
    unsigned short* Xb = (unsigned short*)U4;

    hipMemsetAsync(s1, 0, 2 * NN * sizeof(float), stream);
    k_prep<<<3072 + INPUT * HID / 256, 256, 0, stream>>>(X, W, Xb, Wt);
    k_gemm1<<<dim3(NN / 32, HID / 64), 256, 0, stream>>>(Xb, Wt, a_edge, hT, s1, s2);
    k_attn<<<dim3(NN / 32, 4), 512, 0, stream>>>(adj, s1, s2, hT, U4, denom4);
    k_norm<<<NN, 256, 0, stream>>>(U4, denom4, out);
}